// Round 3
// baseline (6195.929 us; speedup 1.0000x reference)
//
#include <hip/hip_runtime.h>

typedef unsigned short u16;
typedef __attribute__((ext_vector_type(8))) short short8;
typedef __attribute__((ext_vector_type(4))) float f32x4;

#define NN 122880   // nodes per graph
#define EE 245760   // edges per graph
#define BB 4096     // reactions
#define HH 300      // hidden
#define LD 320      // padded feature leading dim (mult of 32)
#define NCP 384     // padded out-col count (3 x 128 tiles)
#define WTSL (NCP * LD)   // elements per transposed-weight slot
#define BHSZ (BB * HH)

__device__ __forceinline__ float b2f(u16 s) {
  union { unsigned int u; float f; } v; v.u = ((unsigned int)s) << 16; return v.f;
}
__device__ __forceinline__ u16 f2b(float f) {
  union { float f; unsigned int u; } v; v.f = f;
  unsigned int r = v.u + 0x7FFFu + ((v.u >> 16) & 1u);
  return (u16)(r >> 16);
}

// ---------------------------------------------------------------------------
// prep: f32 weights -> zero-padded transposed bf16 WT[slot][n(384)][k(320)],
// f32 biases -> padded f32 bias[slot][384]. Slots: 0=Wn 1=We 2..4=W1 5..7=W2
// ---------------------------------------------------------------------------
__global__ __launch_bounds__(256) void prep_kernel(
    const float* __restrict__ Wn, const float* __restrict__ We,
    const float* __restrict__ W1, const float* __restrict__ W2,
    const float* __restrict__ bn, const float* __restrict__ be,
    const float* __restrict__ b1, const float* __restrict__ b2,
    u16* __restrict__ wtAll, float* __restrict__ biasAll)
{
  int idx = blockIdx.x * 256 + threadIdx.x;
  if (idx < 8 * WTSL) {
    int slot = idx / WTSL, rem = idx % WTSL;
    int n = rem / LD, k = rem % LD;
    float v = 0.f;
    if (n < HH) {
      if (slot == 0)      { if (k < 64)  v = Wn[k * HH + n]; }
      else if (slot == 1) { if (k < 16)  v = We[k * HH + n]; }
      else if (slot < 5)  { int l = slot - 2; if (k < HH) v = W1[(l * HH + k) * HH + n]; }
      else                { int l = slot - 5; if (k < HH) v = W2[(l * HH + k) * HH + n]; }
    }
    wtAll[idx] = f2b(v);
  } else {
    int j = idx - 8 * WTSL;
    if (j < 8 * NCP) {
      int slot = j / NCP, n = j % NCP;
      float v = 0.f;
      if (n < HH) {
        const float* bp = (slot == 0) ? bn : (slot == 1) ? be
                         : (slot < 5) ? (b1 + (slot - 2) * HH) : (b2 + (slot - 5) * HH);
        v = bp[n];
      }
      biasAll[j] = v;
    }
  }
}

// f32 -> bf16 pack (vectorized x4)
__global__ __launch_bounds__(256) void cvt_kernel(
    const float4* __restrict__ in, ushort4* __restrict__ out, int n4)
{
  int i = blockIdx.x * 256 + threadIdx.x;
  if (i < n4) {
    float4 v = in[i];
    ushort4 o;
    o.x = f2b(v.x); o.y = f2b(v.y); o.z = f2b(v.z); o.w = f2b(v.w);
    out[i] = o;
  }
}

__global__ __launch_bounds__(256) void zero_kernel(float4* __restrict__ p, int n4) {
  int i = blockIdx.x * 256 + threadIdx.x;
  if (i < n4) p[i] = make_float4(0.f, 0.f, 0.f, 0.f);
}

// ---------------------------------------------------------------------------
// CSR build: counts -> exclusive scan -> fill (dst -> list of edge ids)
// ---------------------------------------------------------------------------
__global__ __launch_bounds__(256) void count_kernel(
    const int* __restrict__ dst, int* __restrict__ counts)
{
  int e = blockIdx.x * 256 + threadIdx.x;
  if (e < EE) atomicAdd(&counts[dst[e]], 1);
}

__global__ __launch_bounds__(1024) void scan_kernel(
    const int* __restrict__ counts, int* __restrict__ indptr, int* __restrict__ cursor)
{
  __shared__ int sd[1024];
  const int tid = threadIdx.x;
  const int base = tid * 120;          // 1024 * 120 == NN exactly
  int s = 0;
  for (int i = 0; i < 120; ++i) s += counts[base + i];
  sd[tid] = s;
  __syncthreads();
  for (int off = 1; off < 1024; off <<= 1) {
    int v = (tid >= off) ? sd[tid - off] : 0;
    __syncthreads();
    sd[tid] += v;
    __syncthreads();
  }
  int run = sd[tid] - s;               // exclusive prefix
  for (int i = 0; i < 120; ++i) {
    indptr[base + i] = run;
    cursor[base + i] = run;
    run += counts[base + i];
  }
  if (tid == 1023) indptr[NN] = run;   // == EE
}

__global__ __launch_bounds__(256) void fill_kernel(
    const int* __restrict__ dst, int* __restrict__ cursor, int* __restrict__ eids)
{
  int e = blockIdx.x * 256 + threadIdx.x;
  if (e < EE) {
    int pos = atomicAdd(&cursor[dst[e]], 1);
    eids[pos] = e;
  }
}

// ---------------------------------------------------------------------------
// Unified MFMA GEMM: C[r,c] = op(A[r,:Ka] @ W[:Ka,c] + bias[c]), bf16 in/out.
// WT: [384][320] transposed weights, zero pads. K mult of 32; chunks with
// kg>=Ka are zero-filled (never loaded). 256 thr, 128x128 tile, 4 waves 2x2.
// ---------------------------------------------------------------------------
__global__ __launch_bounds__(256) void gemm_kernel(
    const u16* __restrict__ A, int lda, int K, int Ka,
    const u16* __restrict__ WT, const float* __restrict__ bias,
    u16* __restrict__ C, int relu)
{
  __shared__ u16 As[128][40];   // +8 pad: rows 80B, 16B-aligned chunks
  __shared__ u16 Bs[128][40];

  const int tid = threadIdx.x;
  const int lane = tid & 63, w = tid >> 6;
  const int wm = (w & 1) * 64, wn = (w >> 1) * 64;
  const int m16 = lane & 15, q = lane >> 4;
  const long r0 = (long)blockIdx.x * 128;
  const int c0 = blockIdx.y * 128;

  f32x4 acc[4][4];
#pragma unroll
  for (int i = 0; i < 4; ++i)
#pragma unroll
    for (int j = 0; j < 4; ++j) acc[i][j] = (f32x4){0.f, 0.f, 0.f, 0.f};

  const int nk = K >> 5;
  for (int kt = 0; kt < nk; ++kt) {
    __syncthreads();
#pragma unroll
    for (int i = 0; i < 2; ++i) {
      int ci = tid + i * 256;
      int row = ci >> 2, kc = (ci & 3) << 3;
      int kg = (kt << 5) + kc;
      uint4 av = make_uint4(0u, 0u, 0u, 0u);
      if (kg < Ka)
        av = *(const uint4*)(A + (r0 + row) * (long)lda + kg);
      *(uint4*)&As[row][kc] = av;
      uint4 bv = *(const uint4*)(WT + (long)(c0 + row) * LD + kg);
      *(uint4*)&Bs[row][kc] = bv;
    }
    __syncthreads();

    short8 af[4], bf[4];
#pragma unroll
    for (int t = 0; t < 4; ++t) af[t] = *(const short8*)&As[wm + t * 16 + m16][q << 3];
#pragma unroll
    for (int t = 0; t < 4; ++t) bf[t] = *(const short8*)&Bs[wn + t * 16 + m16][q << 3];
#pragma unroll
    for (int tm = 0; tm < 4; ++tm)
#pragma unroll
      for (int tn = 0; tn < 4; ++tn)
        acc[tm][tn] = __builtin_amdgcn_mfma_f32_16x16x32_bf16(af[tm], bf[tn], acc[tm][tn], 0, 0, 0);
  }

  // D row = q*4+i, col = lane&15 (m89/m91-verified C/D layout)
#pragma unroll
  for (int tn = 0; tn < 4; ++tn) {
    int c = c0 + wn + tn * 16 + m16;
    if (c >= LD) continue;               // pads c in [300,320) store exact 0
    float bv = bias[c];
#pragma unroll
    for (int tm = 0; tm < 4; ++tm) {
      long rbase = r0 + wm + tm * 16 + q * 4;
#pragma unroll
      for (int i = 0; i < 4; ++i) {
        float v = acc[tm][tn][i] + bv;
        if (relu) v = v > 0.f ? v : 0.f;
        C[(rbase + i) * LD + c] = f2b(v);
      }
    }
  }
}

// ---------------------------------------------------------------------------
// gather (fast path): z[n] = h[n] + sum_{e: dst[e]==n} relu(h[src[e]] + ef[e])
// one wave per node, f32 register accumulation, no atomics.
// ---------------------------------------------------------------------------
__global__ __launch_bounds__(256) void gather_kernel(
    const u16* __restrict__ h, const u16* __restrict__ ef,
    const int* __restrict__ src, const int* __restrict__ indptr,
    const int* __restrict__ eids, u16* __restrict__ z)
{
  int n = blockIdx.x * 4 + (threadIdx.x >> 6);
  int lane = threadIdx.x & 63;
  const u16* hrow = h + (long)n * LD;
  float a[5];
#pragma unroll
  for (int j = 0; j < 5; ++j) {
    int c = lane + 64 * j;
    a[j] = (c < HH) ? b2f(hrow[c]) : 0.f;
  }
  int lo = indptr[n], hi = indptr[n + 1];
  for (int t = lo; t < hi; ++t) {
    int e = eids[t], s = src[e];
    const u16* hs = h + (long)s * LD;
    const u16* er = ef + (long)e * LD;
#pragma unroll
    for (int j = 0; j < 5; ++j) {
      int c = lane + 64 * j;
      if (c < HH) {
        float m = b2f(hs[c]) + b2f(er[c]);
        a[j] += m > 0.f ? m : 0.f;
      }
    }
  }
  u16* zr = z + (long)n * LD;
#pragma unroll
  for (int j = 0; j < 5; ++j) {
    int c = lane + 64 * j;
    if (c < LD) zr[c] = (c < HH) ? f2b(a[j]) : (u16)0;
  }
}

// ---------------------------------------------------------------------------
// gather (small-ws fallback): recompute ef = e@We + be on the fly (K=16)
// from bf16-packed raw edge features; We column-major in LDS.
// ---------------------------------------------------------------------------
__global__ __launch_bounds__(256) void gather_rec_kernel(
    const u16* __restrict__ h, const u16* __restrict__ eraw,
    const u16* __restrict__ wtE, const float* __restrict__ biasE,
    const int* __restrict__ src, const int* __restrict__ indptr,
    const int* __restrict__ eids, u16* __restrict__ z)
{
  __shared__ float WeS[16][304];
  __shared__ float beS[304];
  for (int i = threadIdx.x; i < 16 * 304; i += 256) {
    int k = i / 304, c = i % 304;
    WeS[k][c] = (c < HH) ? b2f(wtE[(long)c * LD + k]) : 0.f;
  }
  for (int i = threadIdx.x; i < 304; i += 256)
    beS[i] = (i < HH) ? biasE[i] : 0.f;
  __syncthreads();

  int n = blockIdx.x * 4 + (threadIdx.x >> 6);
  int lane = threadIdx.x & 63;
  const u16* hrow = h + (long)n * LD;
  float a[5];
#pragma unroll
  for (int j = 0; j < 5; ++j) {
    int c = lane + 64 * j;
    a[j] = (c < HH) ? b2f(hrow[c]) : 0.f;
  }
  int lo = indptr[n], hi = indptr[n + 1];
  for (int t = lo; t < hi; ++t) {
    int e = eids[t], s = src[e];
    const u16* hs = h + (long)s * LD;
    const u16* er = eraw + (long)e * 16;
    float ev[16];
#pragma unroll
    for (int k = 0; k < 16; ++k) ev[k] = b2f(er[k]);
#pragma unroll
    for (int j = 0; j < 5; ++j) {
      int c = lane + 64 * j;
      if (c < HH) {
        float m = beS[c];
#pragma unroll
        for (int k = 0; k < 16; ++k) m += ev[k] * WeS[k][c];
        m += b2f(hs[c]);
        a[j] += m > 0.f ? m : 0.f;
      }
    }
  }
  u16* zr = z + (long)n * LD;
#pragma unroll
  for (int j = 0; j < 5; ++j) {
    int c = lane + 64 * j;
    if (c < LD) zr[c] = (c < HH) ? f2b(a[j]) : (u16)0;
  }
}

// ---------------------------------------------------------------------------
// pooling: seg sorted -> block b binary-searches node range, no atomics
// ---------------------------------------------------------------------------
__global__ __launch_bounds__(320) void pool_kernel(
    const u16* __restrict__ h, const int* __restrict__ seg, float* __restrict__ acc)
{
  int b = blockIdx.x;
  int lo, hi;
  { int l = 0, r = NN; while (l < r) { int m = (l + r) >> 1; if (seg[m] < b) l = m + 1; else r = m; } lo = l; }
  { int l = lo, r = NN; while (l < r) { int m = (l + r) >> 1; if (seg[m] < b + 1) l = m + 1; else r = m; } hi = l; }
  int j = threadIdx.x;
  if (j < HH) {
    float s = 0.f;
    for (int n = lo; n < hi; ++n) s += b2f(h[(long)n * LD + j]);
    acc[(long)b * HH + j] += s;
  }
}

__global__ __launch_bounds__(256) void combine_kernel(
    const float* __restrict__ r, const float* __restrict__ p, float* __restrict__ out)
{
  int i = blockIdx.x * 256 + threadIdx.x;
  if (i < BHSZ) {
    float rv = r[i], pv = p[i];
    out[i] = rv - pv;
    out[BHSZ + i] = rv;
    out[2 * BHSZ + i] = pv;
  }
}

// ---------------------------------------------------------------------------
extern "C" void kernel_launch(void* const* d_in, const int* in_sizes, int n_in,
                              void* d_out, int out_size, void* d_ws, size_t ws_size,
                              hipStream_t stream)
{
  (void)in_sizes; (void)n_in; (void)out_size;
  const float* r_x = (const float*)d_in[0];
  const float* r_e = (const float*)d_in[1];
  const float* p_x = (const float*)d_in[2];
  const float* p_e = (const float*)d_in[3];
  const float* Wn  = (const float*)d_in[4];
  const float* bn  = (const float*)d_in[5];
  const float* We  = (const float*)d_in[6];
  const float* be  = (const float*)d_in[7];
  const float* W1  = (const float*)d_in[8];
  const float* b1  = (const float*)d_in[9];
  const float* W2  = (const float*)d_in[10];
  const float* b2  = (const float*)d_in[11];
  const int* r_src = (const int*)d_in[12];
  const int* r_dst = (const int*)d_in[13];
  const int* r_seg = (const int*)d_in[14];
  const int* p_src = (const int*)d_in[15];
  const int* p_dst = (const int*)d_in[16];
  const int* p_seg = (const int*)d_in[17];
  float* out = (float*)d_out;

  // --- workspace layout, 256B-aligned slots; efb only if it fits ---
  char* ws = (char*)d_ws;
  size_t off = 0;
  auto take = [&](size_t bytes) -> char* {
    char* p = ws + off;
    off = (off + bytes + 255) & ~(size_t)255;
    return p;
  };
  u16*   nb0     = (u16*)  take((size_t)NN * LD * 2);       // h / t ping
  u16*   nb1     = (u16*)  take((size_t)NN * LD * 2);       // z / h pong
  u16*   wtAll   = (u16*)  take((size_t)8 * WTSL * 2);      // transposed weights
  float* biasAll = (float*)take((size_t)8 * NCP * 4);       // padded biases
  float* r_acc   = (float*)take((size_t)BHSZ * 4);
  float* p_acc   = (float*)take((size_t)BHSZ * 4);
  int*   indptr  = (int*)  take((size_t)(NN + 1) * 4);
  int*   cursor  = (int*)  take((size_t)NN * 4);
  int*   counts  = (int*)  take((size_t)NN * 4);
  int*   eids    = (int*)  take((size_t)EE * 4);
  u16*   cvtX    = (u16*)  take((size_t)NN * 64 * 2);       // bf16 x of current graph
  u16*   cvtE    = (u16*)  take((size_t)EE * 16 * 2);       // bf16 e of current graph
  u16*   efb     = (u16*)  take((size_t)EE * LD * 2);       // optional ef buffer
  const bool use_efb = (off <= ws_size);

  prep_kernel<<<3852, 256, 0, stream>>>(Wn, We, W1, W2, bn, be, b1, b2, wtAll, biasAll);
  zero_kernel<<<2400, 256, 0, stream>>>((float4*)r_acc, 614400);   // r_acc + p_acc

  const float* xs[3] = { r_x, r_x + (size_t)NN * 64, p_x };
  const float* es[3] = { r_e, r_e + (size_t)EE * 16, p_e };
  const int* srcs[3] = { r_src, r_src + EE, p_src };
  const int* dsts[3] = { r_dst, r_dst + EE, p_dst };
  const int* segs[3] = { r_seg, r_seg + NN, p_seg };
  float*     accs[3] = { r_acc, r_acc, p_acc };

  for (int g = 0; g < 3; ++g) {
    // CSR by dst (reused across the 3 layers of this graph)
    zero_kernel<<<120, 256, 0, stream>>>((float4*)counts, 30720);
    count_kernel<<<960, 256, 0, stream>>>(dsts[g], counts);
    scan_kernel<<<1, 1024, 0, stream>>>(counts, indptr, cursor);
    fill_kernel<<<960, 256, 0, stream>>>(dsts[g], cursor, eids);

    // f32 -> bf16 input packs
    cvt_kernel<<<7680, 256, 0, stream>>>((const float4*)xs[g], (ushort4*)cvtX, NN * 16);
    cvt_kernel<<<3840, 256, 0, stream>>>((const float4*)es[g], (ushort4*)cvtE, EE * 4);

    // h = relu(x @ Wn + bn)   (K=64)
    gemm_kernel<<<dim3(NN / 128, 3), 256, 0, stream>>>(cvtX, 64, 64, 64,
        wtAll, biasAll, nb0, 1);
    if (use_efb) {
      // ef = e @ We + be      (Ka=16 padded to 32)
      gemm_kernel<<<dim3(EE / 128, 3), 256, 0, stream>>>(cvtE, 16, 32, 16,
          wtAll + WTSL, biasAll + NCP, efb, 0);
    }

    u16* hA = nb0; u16* hB = nb1;
    for (int l = 0; l < 3; ++l) {
      if (use_efb)
        gather_kernel<<<NN / 4, 256, 0, stream>>>(hA, efb, srcs[g], indptr, eids, hB);
      else
        gather_rec_kernel<<<NN / 4, 256, 0, stream>>>(hA, cvtE, wtAll + WTSL,
            biasAll + NCP, srcs[g], indptr, eids, hB);
      // t = relu(z @ W1[l] + b1[l])
      gemm_kernel<<<dim3(NN / 128, 3), 256, 0, stream>>>(hB, LD, LD, LD,
          wtAll + (2 + l) * WTSL, biasAll + (2 + l) * NCP, hA, 1);
      // h = t @ W2[l] + b2[l]  (+relu if l<2)
      gemm_kernel<<<dim3(NN / 128, 3), 256, 0, stream>>>(hA, LD, LD, LD,
          wtAll + (5 + l) * WTSL, biasAll + (5 + l) * NCP, hB, (l < 2) ? 1 : 0);
      u16* tmp = hA; hA = hB; hB = tmp;
    }
    pool_kernel<<<BB, 320, 0, stream>>>(hA, segs[g], accs[g]);
  }
  combine_kernel<<<4800, 256, 0, stream>>>(r_acc, p_acc, out);
}

// Round 4
// 5191.507 us; speedup vs baseline: 1.1935x; 1.1935x over previous
//
#include <hip/hip_runtime.h>

typedef unsigned short u16;
typedef __attribute__((ext_vector_type(8))) short short8;
typedef __attribute__((ext_vector_type(4))) float f32x4;

#define NN 122880   // nodes per graph
#define EE 245760   // edges per graph
#define BB 4096     // reactions
#define HH 300      // hidden
#define LD 320      // padded feature leading dim (mult of 32)
#define NCP 384     // padded out-col count (3 x 128 tiles)
#define WTSL (NCP * LD)   // elements per transposed-weight slot
#define BHSZ (BB * HH)

__device__ __forceinline__ float b2f(u16 s) {
  union { unsigned int u; float f; } v; v.u = ((unsigned int)s) << 16; return v.f;
}
__device__ __forceinline__ u16 f2b(float f) {
  union { float f; unsigned int u; } v; v.f = f;
  unsigned int r = v.u + 0x7FFFu + ((v.u >> 16) & 1u);
  return (u16)(r >> 16);
}

// ---------------------------------------------------------------------------
// prep: f32 weights -> zero-padded transposed bf16 WT[slot][n(384)][k(320)],
// f32 biases -> padded f32 bias[slot][384]. Slots: 0=Wn 1=We 2..4=W1 5..7=W2
// ---------------------------------------------------------------------------
__global__ __launch_bounds__(256) void prep_kernel(
    const float* __restrict__ Wn, const float* __restrict__ We,
    const float* __restrict__ W1, const float* __restrict__ W2,
    const float* __restrict__ bn, const float* __restrict__ be,
    const float* __restrict__ b1, const float* __restrict__ b2,
    u16* __restrict__ wtAll, float* __restrict__ biasAll)
{
  int idx = blockIdx.x * 256 + threadIdx.x;
  if (idx < 8 * WTSL) {
    int slot = idx / WTSL, rem = idx % WTSL;
    int n = rem / LD, k = rem % LD;
    float v = 0.f;
    if (n < HH) {
      if (slot == 0)      { if (k < 64)  v = Wn[k * HH + n]; }
      else if (slot == 1) { if (k < 16)  v = We[k * HH + n]; }
      else if (slot < 5)  { int l = slot - 2; if (k < HH) v = W1[(l * HH + k) * HH + n]; }
      else                { int l = slot - 5; if (k < HH) v = W2[(l * HH + k) * HH + n]; }
    }
    wtAll[idx] = f2b(v);
  } else {
    int j = idx - 8 * WTSL;
    if (j < 8 * NCP) {
      int slot = j / NCP, n = j % NCP;
      float v = 0.f;
      if (n < HH) {
        const float* bp = (slot == 0) ? bn : (slot == 1) ? be
                         : (slot < 5) ? (b1 + (slot - 2) * HH) : (b2 + (slot - 5) * HH);
        v = bp[n];
      }
      biasAll[j] = v;
    }
  }
}

__global__ __launch_bounds__(256) void zero_kernel(float4* __restrict__ p, int n4) {
  int i = blockIdx.x * 256 + threadIdx.x;
  if (i < n4) p[i] = make_float4(0.f, 0.f, 0.f, 0.f);
}

// ---------------------------------------------------------------------------
// CSR build: cursor doubles as counts; scan converts in place.
// ---------------------------------------------------------------------------
__global__ __launch_bounds__(256) void count_kernel(
    const int* __restrict__ dst, int* __restrict__ cursor)
{
  int e = blockIdx.x * 256 + threadIdx.x;
  if (e < EE) atomicAdd(&cursor[dst[e]], 1);
}

__global__ __launch_bounds__(1024) void scan_kernel(
    int* __restrict__ cursor, int* __restrict__ indptr)
{
  __shared__ int sd[1024];
  const int tid = threadIdx.x;
  const int base = tid * 120;          // 1024 * 120 == NN exactly
  int s = 0;
  for (int i = 0; i < 120; ++i) s += cursor[base + i];
  sd[tid] = s;
  __syncthreads();
  for (int off = 1; off < 1024; off <<= 1) {
    int v = (tid >= off) ? sd[tid - off] : 0;
    __syncthreads();
    sd[tid] += v;
    __syncthreads();
  }
  int run = sd[tid] - s;               // exclusive prefix
  for (int i = 0; i < 120; ++i) {
    int c = cursor[base + i];
    indptr[base + i] = run;
    cursor[base + i] = run;
    run += c;
  }
  if (tid == 1023) indptr[NN] = run;   // == EE
}

__global__ __launch_bounds__(256) void fill_kernel(
    const int* __restrict__ dst, int* __restrict__ cursor, int* __restrict__ eids)
{
  int e = blockIdx.x * 256 + threadIdx.x;
  if (e < EE) {
    int pos = atomicAdd(&cursor[dst[e]], 1);
    eids[pos] = e;
  }
}

// ---------------------------------------------------------------------------
// Unified MFMA GEMM: C[r,c] = op(A[r,:K] @ W[:K,c] + bias[c]), bf16 out.
// A is bf16 (a_f32=0, lda in u16 elems) or f32 (a_f32=1, lda in f32 elems;
// converted during LDS staging). WT: [384][320] transposed bf16, zero pads.
// 256 thr, 128x128 tile, 4 waves 2x2, each 64x64 via 4x4 MFMA 16x16x32.
// ---------------------------------------------------------------------------
__global__ __launch_bounds__(256) void gemm_kernel(
    const void* __restrict__ A, int lda, int K, int a_f32,
    const u16* __restrict__ WT, const float* __restrict__ bias,
    u16* __restrict__ C, int relu)
{
  __shared__ u16 As[128][40];   // +8 pad: rows 80B, 16B-aligned chunks
  __shared__ u16 Bs[128][40];

  const int tid = threadIdx.x;
  const int lane = tid & 63, w = tid >> 6;
  const int wm = (w & 1) * 64, wn = (w >> 1) * 64;
  const int m16 = lane & 15, q = lane >> 4;
  const long r0 = (long)blockIdx.x * 128;
  const int c0 = blockIdx.y * 128;

  f32x4 acc[4][4];
#pragma unroll
  for (int i = 0; i < 4; ++i)
#pragma unroll
    for (int j = 0; j < 4; ++j) acc[i][j] = (f32x4){0.f, 0.f, 0.f, 0.f};

  const int nk = K >> 5;
  for (int kt = 0; kt < nk; ++kt) {
    __syncthreads();
#pragma unroll
    for (int i = 0; i < 2; ++i) {
      int ci = tid + i * 256;
      int row = ci >> 2, kc = (ci & 3) << 3;
      int kg = (kt << 5) + kc;
      if (a_f32) {
        const float* Af = (const float*)A + (r0 + row) * (long)lda + kg;
        float4 v0 = *(const float4*)Af;
        float4 v1 = *(const float4*)(Af + 4);
        ushort4 p0, p1;
        p0.x = f2b(v0.x); p0.y = f2b(v0.y); p0.z = f2b(v0.z); p0.w = f2b(v0.w);
        p1.x = f2b(v1.x); p1.y = f2b(v1.y); p1.z = f2b(v1.z); p1.w = f2b(v1.w);
        *(ushort4*)&As[row][kc] = p0;
        *(ushort4*)&As[row][kc + 4] = p1;
      } else {
        uint4 av = *(const uint4*)((const u16*)A + (r0 + row) * (long)lda + kg);
        *(uint4*)&As[row][kc] = av;
      }
      uint4 bv = *(const uint4*)(WT + (long)(c0 + row) * LD + kg);
      *(uint4*)&Bs[row][kc] = bv;
    }
    __syncthreads();

    short8 af[4], bf[4];
#pragma unroll
    for (int t = 0; t < 4; ++t) af[t] = *(const short8*)&As[wm + t * 16 + m16][q << 3];
#pragma unroll
    for (int t = 0; t < 4; ++t) bf[t] = *(const short8*)&Bs[wn + t * 16 + m16][q << 3];
#pragma unroll
    for (int tm = 0; tm < 4; ++tm)
#pragma unroll
      for (int tn = 0; tn < 4; ++tn)
        acc[tm][tn] = __builtin_amdgcn_mfma_f32_16x16x32_bf16(af[tm], bf[tn], acc[tm][tn], 0, 0, 0);
  }

  // D row = q*4+i, col = lane&15 (m89/m91-verified C/D layout)
#pragma unroll
  for (int tn = 0; tn < 4; ++tn) {
    int c = c0 + wn + tn * 16 + m16;
    if (c >= LD) continue;               // pads c in [300,320) store exact 0
    float bv = bias[c];
#pragma unroll
    for (int tm = 0; tm < 4; ++tm) {
      long rbase = r0 + wm + tm * 16 + q * 4;
#pragma unroll
      for (int i = 0; i < 4; ++i) {
        float v = acc[tm][tn][i] + bv;
        if (relu) v = v > 0.f ? v : 0.f;
        C[(rbase + i) * LD + c] = f2b(v);
      }
    }
  }
}

// ---------------------------------------------------------------------------
// gather: z[n] = h[n] + sum_{e: dst[e]==n} relu(h[src[e]] + e_raw[e]@We + be)
// One 320-thread block per node; thread c owns output column c. Per-thread
// We column (16 bf16 -> f32) + bias hoisted into registers; per edge: 4x
// float4 broadcast loads of the raw f32 edge vec + 16 reg FMAs + 1 coalesced
// h_src load. No LDS in the edge loop, no atomics.
// ---------------------------------------------------------------------------
__global__ __launch_bounds__(320) void gather_kernel(
    const u16* __restrict__ h, const float* __restrict__ eraw,
    const u16* __restrict__ wtE, const float* __restrict__ biasE,
    const int* __restrict__ src, const int* __restrict__ indptr,
    const int* __restrict__ eids, u16* __restrict__ z)
{
  const int n = blockIdx.x;
  const int c = threadIdx.x;
  const bool act = (c < HH);

  // hoist We[:,c] and be[c]
  float wreg[16];
  {
    uint4 w0 = *(const uint4*)(wtE + (long)c * LD);       // k 0..7
    uint4 w1 = *(const uint4*)(wtE + (long)c * LD + 8);   // k 8..15
    const u16* pw0 = (const u16*)&w0;
    const u16* pw1 = (const u16*)&w1;
#pragma unroll
    for (int k = 0; k < 8; ++k) { wreg[k] = b2f(pw0[k]); wreg[8 + k] = b2f(pw1[k]); }
  }
  const float bv = biasE[c];

  float a = act ? b2f(h[(long)n * LD + c]) : 0.f;

  const int lo = indptr[n], hi = indptr[n + 1];
  for (int t = lo; t < hi; ++t) {
    int e = eids[t];
    int s = src[e];
    const float* er = eraw + (long)e * 16;
    float4 e0 = *(const float4*)er;
    float4 e1 = *(const float4*)(er + 4);
    float4 e2 = *(const float4*)(er + 8);
    float4 e3 = *(const float4*)(er + 12);
    float hs = act ? b2f(h[(long)s * LD + c]) : 0.f;
    float m = bv;
    m += e0.x * wreg[0];  m += e0.y * wreg[1];  m += e0.z * wreg[2];  m += e0.w * wreg[3];
    m += e1.x * wreg[4];  m += e1.y * wreg[5];  m += e1.z * wreg[6];  m += e1.w * wreg[7];
    m += e2.x * wreg[8];  m += e2.y * wreg[9];  m += e2.z * wreg[10]; m += e2.w * wreg[11];
    m += e3.x * wreg[12]; m += e3.y * wreg[13]; m += e3.z * wreg[14]; m += e3.w * wreg[15];
    m += hs;
    a += (m > 0.f) ? m : 0.f;
  }
  z[(long)n * LD + c] = act ? f2b(a) : (u16)0;
}

// ---------------------------------------------------------------------------
// pooling: seg sorted -> block b binary-searches node range, no atomics
// ---------------------------------------------------------------------------
__global__ __launch_bounds__(320) void pool_kernel(
    const u16* __restrict__ h, const int* __restrict__ seg, float* __restrict__ acc)
{
  int b = blockIdx.x;
  int lo, hi;
  { int l = 0, r = NN; while (l < r) { int m = (l + r) >> 1; if (seg[m] < b) l = m + 1; else r = m; } lo = l; }
  { int l = lo, r = NN; while (l < r) { int m = (l + r) >> 1; if (seg[m] < b + 1) l = m + 1; else r = m; } hi = l; }
  int j = threadIdx.x;
  if (j < HH) {
    float s = 0.f;
    for (int n = lo; n < hi; ++n) s += b2f(h[(long)n * LD + j]);
    acc[(long)b * HH + j] += s;
  }
}

// out[0:BHSZ) = r - p, where r lives at out[BHSZ..) and p at out[2*BHSZ..)
__global__ __launch_bounds__(256) void combine_kernel(float* __restrict__ out) {
  int i = blockIdx.x * 256 + threadIdx.x;
  if (i < BHSZ) out[i] = out[BHSZ + i] - out[2 * BHSZ + i];
}

// ---------------------------------------------------------------------------
extern "C" void kernel_launch(void* const* d_in, const int* in_sizes, int n_in,
                              void* d_out, int out_size, void* d_ws, size_t ws_size,
                              hipStream_t stream)
{
  (void)in_sizes; (void)n_in; (void)out_size; (void)ws_size;
  const float* r_x = (const float*)d_in[0];
  const float* r_e = (const float*)d_in[1];
  const float* p_x = (const float*)d_in[2];
  const float* p_e = (const float*)d_in[3];
  const float* Wn  = (const float*)d_in[4];
  const float* bn  = (const float*)d_in[5];
  const float* We  = (const float*)d_in[6];
  const float* be  = (const float*)d_in[7];
  const float* W1  = (const float*)d_in[8];
  const float* b1  = (const float*)d_in[9];
  const float* W2  = (const float*)d_in[10];
  const float* b2  = (const float*)d_in[11];
  const int* r_src = (const int*)d_in[12];
  const int* r_dst = (const int*)d_in[13];
  const int* r_seg = (const int*)d_in[14];
  const int* p_src = (const int*)d_in[15];
  const int* p_dst = (const int*)d_in[16];
  const int* p_seg = (const int*)d_in[17];
  float* out = (float*)d_out;

  // --- workspace layout (~161 MB) ---
  char* ws = (char*)d_ws;
  size_t off = 0;
  auto take = [&](size_t bytes) -> char* {
    char* p = ws + off;
    off = (off + bytes + 255) & ~(size_t)255;
    return p;
  };
  u16*   nb0     = (u16*)  take((size_t)NN * LD * 2);       // h / t ping
  u16*   nb1     = (u16*)  take((size_t)NN * LD * 2);       // z / h pong
  u16*   wtAll   = (u16*)  take((size_t)8 * WTSL * 2);      // transposed weights
  float* biasAll = (float*)take((size_t)8 * NCP * 4);       // padded biases
  int*   indptr  = (int*)  take((size_t)(NN + 1) * 4);
  int*   cursor  = (int*)  take((size_t)NN * 4);
  int*   eids    = (int*)  take((size_t)EE * 4);

  float* r_acc = out + BHSZ;       // pooled reactant sums (f32, also output 1)
  float* p_acc = out + 2 * BHSZ;   // pooled product sums  (f32, also output 2)

  prep_kernel<<<3852, 256, 0, stream>>>(Wn, We, W1, W2, bn, be, b1, b2, wtAll, biasAll);
  zero_kernel<<<2400, 256, 0, stream>>>((float4*)r_acc, 614400);   // r_acc + p_acc

  const float* xs[3] = { r_x, r_x + (size_t)NN * 64, p_x };
  const float* es[3] = { r_e, r_e + (size_t)EE * 16, p_e };
  const int* srcs[3] = { r_src, r_src + EE, p_src };
  const int* dsts[3] = { r_dst, r_dst + EE, p_dst };
  const int* segs[3] = { r_seg, r_seg + NN, p_seg };
  float*     accs[3] = { r_acc, r_acc, p_acc };

  for (int g = 0; g < 3; ++g) {
    // CSR by dst (reused across the 3 layers of this graph)
    zero_kernel<<<120, 256, 0, stream>>>((float4*)cursor, 30720);
    count_kernel<<<960, 256, 0, stream>>>(dsts[g], cursor);
    scan_kernel<<<1, 1024, 0, stream>>>(cursor, indptr);
    fill_kernel<<<960, 256, 0, stream>>>(dsts[g], cursor, eids);

    // h = relu(x @ Wn + bn)   (f32 A, K=64)
    gemm_kernel<<<dim3(NN / 128, 3), 256, 0, stream>>>(xs[g], 64, 64, 1,
        wtAll, biasAll, nb0, 1);

    u16* hA = nb0; u16* hB = nb1;
    for (int l = 0; l < 3; ++l) {
      gather_kernel<<<NN, 320, 0, stream>>>(hA, es[g], wtAll + WTSL,
          biasAll + NCP, srcs[g], indptr, eids, hB);
      // t = relu(z @ W1[l] + b1[l])
      gemm_kernel<<<dim3(NN / 128, 3), 256, 0, stream>>>(hB, LD, LD, 0,
          wtAll + (2 + l) * WTSL, biasAll + (2 + l) * NCP, hA, 1);
      // h = t @ W2[l] + b2[l]  (+relu if l<2)
      gemm_kernel<<<dim3(NN / 128, 3), 256, 0, stream>>>(hA, LD, LD, 0,
          wtAll + (5 + l) * WTSL, biasAll + (5 + l) * NCP, hB, (l < 2) ? 1 : 0);
      u16* tmp = hA; hA = hB; hB = tmp;
    }
    pool_kernel<<<BB, 320, 0, stream>>>(hA, segs[g], accs[g]);
  }
  combine_kernel<<<4800, 256, 0, stream>>>(out);
}

// Round 5
// 4073.138 us; speedup vs baseline: 1.5212x; 1.2746x over previous
//
#include <hip/hip_runtime.h>

typedef unsigned short u16;
typedef __attribute__((ext_vector_type(8))) short short8;
typedef __attribute__((ext_vector_type(4))) float f32x4;

#define NN 122880   // nodes per graph
#define EE 245760   // edges per graph
#define BB 4096     // reactions
#define HH 300      // hidden
#define LD 320      // padded feature leading dim (mult of 32)
#define NCP 384     // padded out-col count (3 x 128 tiles)
#define WTSL (NCP * LD)   // elements per transposed-weight slot
#define BHSZ (BB * HH)
#define NPB 8       // nodes per gather block

__device__ __forceinline__ float b2f(u16 s) {
  union { unsigned int u; float f; } v; v.u = ((unsigned int)s) << 16; return v.f;
}
__device__ __forceinline__ u16 f2b(float f) {
  union { float f; unsigned int u; } v; v.f = f;
  unsigned int r = v.u + 0x7FFFu + ((v.u >> 16) & 1u);
  return (u16)(r >> 16);
}

// ---------------------------------------------------------------------------
// prep: f32 weights -> zero-padded transposed bf16 WT[slot][n(384)][k(320)],
// f32 biases -> padded f32 bias[slot][384]. Slots: 0=Wn 1=We 2..4=W1 5..7=W2
// ---------------------------------------------------------------------------
__global__ __launch_bounds__(256) void prep_kernel(
    const float* __restrict__ Wn, const float* __restrict__ We,
    const float* __restrict__ W1, const float* __restrict__ W2,
    const float* __restrict__ bn, const float* __restrict__ be,
    const float* __restrict__ b1, const float* __restrict__ b2,
    u16* __restrict__ wtAll, float* __restrict__ biasAll)
{
  int idx = blockIdx.x * 256 + threadIdx.x;
  if (idx < 8 * WTSL) {
    int slot = idx / WTSL, rem = idx % WTSL;
    int n = rem / LD, k = rem % LD;
    float v = 0.f;
    if (n < HH) {
      if (slot == 0)      { if (k < 64)  v = Wn[k * HH + n]; }
      else if (slot == 1) { if (k < 16)  v = We[k * HH + n]; }
      else if (slot < 5)  { int l = slot - 2; if (k < HH) v = W1[(l * HH + k) * HH + n]; }
      else                { int l = slot - 5; if (k < HH) v = W2[(l * HH + k) * HH + n]; }
    }
    wtAll[idx] = f2b(v);
  } else {
    int j = idx - 8 * WTSL;
    if (j < 8 * NCP) {
      int slot = j / NCP, n = j % NCP;
      float v = 0.f;
      if (n < HH) {
        const float* bp = (slot == 0) ? bn : (slot == 1) ? be
                         : (slot < 5) ? (b1 + (slot - 2) * HH) : (b2 + (slot - 5) * HH);
        v = bp[n];
      }
      biasAll[j] = v;
    }
  }
}

__global__ __launch_bounds__(256) void zero_kernel(float4* __restrict__ p, int n4) {
  int i = blockIdx.x * 256 + threadIdx.x;
  if (i < n4) p[i] = make_float4(0.f, 0.f, 0.f, 0.f);
}

// ---------------------------------------------------------------------------
// CSR build: cursor doubles as counts; scan converts in place.
// fill writes both edge ids (for eraw gather) and src node ids, dst-sorted.
// ---------------------------------------------------------------------------
__global__ __launch_bounds__(256) void count_kernel(
    const int* __restrict__ dst, int* __restrict__ cursor)
{
  int e = blockIdx.x * 256 + threadIdx.x;
  if (e < EE) atomicAdd(&cursor[dst[e]], 1);
}

__global__ __launch_bounds__(1024) void scan_kernel(
    int* __restrict__ cursor, int* __restrict__ indptr)
{
  __shared__ int sd[1024];
  const int tid = threadIdx.x;
  const int base = tid * 120;          // 1024 * 120 == NN exactly
  int s = 0;
  for (int i = 0; i < 120; ++i) s += cursor[base + i];
  sd[tid] = s;
  __syncthreads();
  for (int off = 1; off < 1024; off <<= 1) {
    int v = (tid >= off) ? sd[tid - off] : 0;
    __syncthreads();
    sd[tid] += v;
    __syncthreads();
  }
  int run = sd[tid] - s;               // exclusive prefix
  for (int i = 0; i < 120; ++i) {
    int c = cursor[base + i];
    indptr[base + i] = run;
    cursor[base + i] = run;
    run += c;
  }
  if (tid == 1023) indptr[NN] = run;   // == EE
}

__global__ __launch_bounds__(256) void fill_kernel(
    const int* __restrict__ dst, const int* __restrict__ src,
    int* __restrict__ cursor, int* __restrict__ eids, int* __restrict__ ssrt)
{
  int e = blockIdx.x * 256 + threadIdx.x;
  if (e < EE) {
    int pos = atomicAdd(&cursor[dst[e]], 1);
    eids[pos] = e;
    ssrt[pos] = src[e];
  }
}

// ---------------------------------------------------------------------------
// Unified MFMA GEMM: C[r,c] = op(A[arow(r),:Ka] @ W[:Ka,c] + bias[c]), bf16 out.
// A bf16 (a_f32=0) or f32 (a_f32=1, converted in staging). rowidx: optional
// A-row indirection (arow = rowidx[r]). kg >= Ka chunks are zero-filled.
// WT: [384][320] transposed bf16, zero pads. 256 thr, 128x128 tile, 4 waves.
// ---------------------------------------------------------------------------
__global__ __launch_bounds__(256) void gemm_kernel(
    const void* __restrict__ A, int lda, int K, int Ka, int a_f32,
    const int* __restrict__ rowidx,
    const u16* __restrict__ WT, const float* __restrict__ bias,
    u16* __restrict__ C, int relu)
{
  __shared__ u16 As[128][40];   // +8 pad: rows 80B, 16B-aligned chunks
  __shared__ u16 Bs[128][40];

  const int tid = threadIdx.x;
  const int lane = tid & 63, w = tid >> 6;
  const int wm = (w & 1) * 64, wn = (w >> 1) * 64;
  const int m16 = lane & 15, q = lane >> 4;
  const long r0 = (long)blockIdx.x * 128;
  const int c0 = blockIdx.y * 128;

  f32x4 acc[4][4];
#pragma unroll
  for (int i = 0; i < 4; ++i)
#pragma unroll
    for (int j = 0; j < 4; ++j) acc[i][j] = (f32x4){0.f, 0.f, 0.f, 0.f};

  const int nk = K >> 5;
  for (int kt = 0; kt < nk; ++kt) {
    __syncthreads();
#pragma unroll
    for (int i = 0; i < 2; ++i) {
      int ci = tid + i * 256;
      int row = ci >> 2, kc = (ci & 3) << 3;
      int kg = (kt << 5) + kc;
      long arow = r0 + row;
      if (rowidx) arow = rowidx[arow];
      if (kg >= Ka) {
        *(uint4*)&As[row][kc] = make_uint4(0u, 0u, 0u, 0u);
      } else if (a_f32) {
        const float* Af = (const float*)A + arow * (long)lda + kg;
        float4 v0 = *(const float4*)Af;
        float4 v1 = *(const float4*)(Af + 4);
        ushort4 p0, p1;
        p0.x = f2b(v0.x); p0.y = f2b(v0.y); p0.z = f2b(v0.z); p0.w = f2b(v0.w);
        p1.x = f2b(v1.x); p1.y = f2b(v1.y); p1.z = f2b(v1.z); p1.w = f2b(v1.w);
        *(ushort4*)&As[row][kc] = p0;
        *(ushort4*)&As[row][kc + 4] = p1;
      } else {
        uint4 av = *(const uint4*)((const u16*)A + arow * (long)lda + kg);
        *(uint4*)&As[row][kc] = av;
      }
      uint4 bv = *(const uint4*)(WT + (long)(c0 + row) * LD + kg);
      *(uint4*)&Bs[row][kc] = bv;
    }
    __syncthreads();

    short8 af[4], bf[4];
#pragma unroll
    for (int t = 0; t < 4; ++t) af[t] = *(const short8*)&As[wm + t * 16 + m16][q << 3];
#pragma unroll
    for (int t = 0; t < 4; ++t) bf[t] = *(const short8*)&Bs[wn + t * 16 + m16][q << 3];
#pragma unroll
    for (int tm = 0; tm < 4; ++tm)
#pragma unroll
      for (int tn = 0; tn < 4; ++tn)
        acc[tm][tn] = __builtin_amdgcn_mfma_f32_16x16x32_bf16(af[tm], bf[tn], acc[tm][tn], 0, 0, 0);
  }

  // D row = q*4+i, col = lane&15 (m89/m91-verified C/D layout)
#pragma unroll
  for (int tn = 0; tn < 4; ++tn) {
    int c = c0 + wn + tn * 16 + m16;
    if (c >= LD) continue;               // pads c in [300,320) store exact 0
    float bv = bias[c];
#pragma unroll
    for (int tm = 0; tm < 4; ++tm) {
      long rbase = r0 + wm + tm * 16 + q * 4;
#pragma unroll
      for (int i = 0; i < 4; ++i) {
        float v = acc[tm][tn][i] + bv;
        if (relu) v = v > 0.f ? v : 0.f;
        C[(rbase + i) * LD + c] = f2b(v);
      }
    }
  }
}

// ---------------------------------------------------------------------------
// gather fast path: efs holds dst-sorted projected edge features (bias incl).
// z[n] = h[n] + sum_{t in [indptr[n],indptr[n+1])} relu(h[ssrt[t]] + efs[t])
// 320-thread block = 1 column each, NPB nodes serially; efs reads are
// sequential+coalesced, h[src] reads coalesced rows. No LDS, no atomics.
// ---------------------------------------------------------------------------
__global__ __launch_bounds__(320) void gather_fast_kernel(
    const u16* __restrict__ h, const u16* __restrict__ efs,
    const int* __restrict__ ssrt, const int* __restrict__ indptr,
    u16* __restrict__ z)
{
  const int base = blockIdx.x * NPB;
  const int c = threadIdx.x;
  const bool act = (c < HH);
  for (int g = 0; g < NPB; ++g) {
    const int n = base + g;
    const int lo = indptr[n], hi = indptr[n + 1];
    float a = act ? b2f(h[(long)n * LD + c]) : 0.f;
    for (int t = lo; t < hi; ++t) {
      int s = ssrt[t];
      float m = b2f(efs[(long)t * LD + c]) + (act ? b2f(h[(long)s * LD + c]) : 0.f);
      a += (m > 0.f) ? m : 0.f;
    }
    z[(long)n * LD + c] = act ? f2b(a) : (u16)0;
  }
}

// ---------------------------------------------------------------------------
// gather fallback (small ws): recompute ef = eraw@We + be per edge from
// registers; We/bias hoisted once per block (amortized over NPB nodes).
// ---------------------------------------------------------------------------
__global__ __launch_bounds__(320) void gather_fb_kernel(
    const u16* __restrict__ h, const float* __restrict__ eraw,
    const u16* __restrict__ wtE, const float* __restrict__ biasE,
    const int* __restrict__ eids, const int* __restrict__ ssrt,
    const int* __restrict__ indptr, u16* __restrict__ z)
{
  const int base = blockIdx.x * NPB;
  const int c = threadIdx.x;
  const bool act = (c < HH);

  float wreg[16];
  {
    uint4 w0 = *(const uint4*)(wtE + (long)c * LD);
    uint4 w1 = *(const uint4*)(wtE + (long)c * LD + 8);
    const u16* pw0 = (const u16*)&w0;
    const u16* pw1 = (const u16*)&w1;
#pragma unroll
    for (int k = 0; k < 8; ++k) { wreg[k] = b2f(pw0[k]); wreg[8 + k] = b2f(pw1[k]); }
  }
  const float bv = biasE[c];

  for (int g = 0; g < NPB; ++g) {
    const int n = base + g;
    const int lo = indptr[n], hi = indptr[n + 1];
    float a = act ? b2f(h[(long)n * LD + c]) : 0.f;
    for (int t = lo; t < hi; ++t) {
      int e = eids[t];
      int s = ssrt[t];
      const float* er = eraw + (long)e * 16;
      float4 e0 = *(const float4*)er;
      float4 e1 = *(const float4*)(er + 4);
      float4 e2 = *(const float4*)(er + 8);
      float4 e3 = *(const float4*)(er + 12);
      float hs = act ? b2f(h[(long)s * LD + c]) : 0.f;
      float m = bv;
      m += e0.x * wreg[0];  m += e0.y * wreg[1];  m += e0.z * wreg[2];  m += e0.w * wreg[3];
      m += e1.x * wreg[4];  m += e1.y * wreg[5];  m += e1.z * wreg[6];  m += e1.w * wreg[7];
      m += e2.x * wreg[8];  m += e2.y * wreg[9];  m += e2.z * wreg[10]; m += e2.w * wreg[11];
      m += e3.x * wreg[12]; m += e3.y * wreg[13]; m += e3.z * wreg[14]; m += e3.w * wreg[15];
      m += hs;
      a += (m > 0.f) ? m : 0.f;
    }
    z[(long)n * LD + c] = act ? f2b(a) : (u16)0;
  }
}

// ---------------------------------------------------------------------------
// pooling: seg sorted -> block b binary-searches node range, no atomics
// ---------------------------------------------------------------------------
__global__ __launch_bounds__(320) void pool_kernel(
    const u16* __restrict__ h, const int* __restrict__ seg, float* __restrict__ acc)
{
  int b = blockIdx.x;
  int lo, hi;
  { int l = 0, r = NN; while (l < r) { int m = (l + r) >> 1; if (seg[m] < b) l = m + 1; else r = m; } lo = l; }
  { int l = lo, r = NN; while (l < r) { int m = (l + r) >> 1; if (seg[m] < b + 1) l = m + 1; else r = m; } hi = l; }
  int j = threadIdx.x;
  if (j < HH) {
    float s = 0.f;
    for (int n = lo; n < hi; ++n) s += b2f(h[(long)n * LD + j]);
    acc[(long)b * HH + j] += s;
  }
}

// out[0:BHSZ) = r - p, where r lives at out[BHSZ..) and p at out[2*BHSZ..)
__global__ __launch_bounds__(256) void combine_kernel(float* __restrict__ out) {
  int i = blockIdx.x * 256 + threadIdx.x;
  if (i < BHSZ) out[i] = out[BHSZ + i] - out[2 * BHSZ + i];
}

// ---------------------------------------------------------------------------
extern "C" void kernel_launch(void* const* d_in, const int* in_sizes, int n_in,
                              void* d_out, int out_size, void* d_ws, size_t ws_size,
                              hipStream_t stream)
{
  (void)in_sizes; (void)n_in; (void)out_size;
  const float* r_x = (const float*)d_in[0];
  const float* r_e = (const float*)d_in[1];
  const float* p_x = (const float*)d_in[2];
  const float* p_e = (const float*)d_in[3];
  const float* Wn  = (const float*)d_in[4];
  const float* bn  = (const float*)d_in[5];
  const float* We  = (const float*)d_in[6];
  const float* be  = (const float*)d_in[7];
  const float* W1  = (const float*)d_in[8];
  const float* b1  = (const float*)d_in[9];
  const float* W2  = (const float*)d_in[10];
  const float* b2  = (const float*)d_in[11];
  const int* r_src = (const int*)d_in[12];
  const int* r_dst = (const int*)d_in[13];
  const int* r_seg = (const int*)d_in[14];
  const int* p_src = (const int*)d_in[15];
  const int* p_dst = (const int*)d_in[16];
  const int* p_seg = (const int*)d_in[17];
  float* out = (float*)d_out;

  // --- workspace layout (base ~163 MB; efs fast-path +157 MB if it fits) ---
  char* ws = (char*)d_ws;
  size_t off = 0;
  auto take = [&](size_t bytes) -> char* {
    char* p = ws + off;
    off = (off + bytes + 255) & ~(size_t)255;
    return p;
  };
  u16*   nb0     = (u16*)  take((size_t)NN * LD * 2);       // h / t ping
  u16*   nb1     = (u16*)  take((size_t)NN * LD * 2);       // z / h pong
  u16*   wtAll   = (u16*)  take((size_t)8 * WTSL * 2);      // transposed weights
  float* biasAll = (float*)take((size_t)8 * NCP * 4);       // padded biases
  int*   indptr  = (int*)  take((size_t)(NN + 1) * 4);
  int*   cursor  = (int*)  take((size_t)NN * 4);
  int*   eids    = (int*)  take((size_t)EE * 4);            // dst-sorted edge ids
  int*   ssrt    = (int*)  take((size_t)EE * 4);            // dst-sorted src ids
  u16*   efs     = (u16*)  take((size_t)EE * LD * 2);       // optional sorted ef
  const bool use_efs = (off <= ws_size);

  float* r_acc = out + BHSZ;       // pooled reactant sums (f32, output 1)
  float* p_acc = out + 2 * BHSZ;   // pooled product sums  (f32, output 2)

  prep_kernel<<<3852, 256, 0, stream>>>(Wn, We, W1, W2, bn, be, b1, b2, wtAll, biasAll);
  zero_kernel<<<2400, 256, 0, stream>>>((float4*)r_acc, 614400);   // r_acc + p_acc

  const float* xs[3] = { r_x, r_x + (size_t)NN * 64, p_x };
  const float* es[3] = { r_e, r_e + (size_t)EE * 16, p_e };
  const int* srcs[3] = { r_src, r_src + EE, p_src };
  const int* dsts[3] = { r_dst, r_dst + EE, p_dst };
  const int* segs[3] = { r_seg, r_seg + NN, p_seg };
  float*     accs[3] = { r_acc, r_acc, p_acc };

  for (int g = 0; g < 3; ++g) {
    // CSR by dst (reused across the 3 layers of this graph)
    zero_kernel<<<120, 256, 0, stream>>>((float4*)cursor, 30720);
    count_kernel<<<960, 256, 0, stream>>>(dsts[g], cursor);
    scan_kernel<<<1, 1024, 0, stream>>>(cursor, indptr);
    fill_kernel<<<960, 256, 0, stream>>>(dsts[g], srcs[g], cursor, eids, ssrt);

    // h = relu(x @ Wn + bn)   (f32 A, K=64)
    gemm_kernel<<<dim3(NN / 128, 3), 256, 0, stream>>>(xs[g], 64, 64, 64, 1,
        (const int*)nullptr, wtAll, biasAll, nb0, 1);
    if (use_efs) {
      // efs[t] = eraw[eids[t]] @ We + be   (dst-sorted, K=16 padded to 32)
      gemm_kernel<<<dim3(EE / 128, 3), 256, 0, stream>>>(es[g], 16, 32, 16, 1,
          eids, wtAll + WTSL, biasAll + NCP, efs, 0);
    }

    u16* hA = nb0; u16* hB = nb1;
    for (int l = 0; l < 3; ++l) {
      if (use_efs)
        gather_fast_kernel<<<NN / NPB, 320, 0, stream>>>(hA, efs, ssrt, indptr, hB);
      else
        gather_fb_kernel<<<NN / NPB, 320, 0, stream>>>(hA, es[g], wtAll + WTSL,
            biasAll + NCP, eids, ssrt, indptr, hB);
      // t = relu(z @ W1[l] + b1[l])
      gemm_kernel<<<dim3(NN / 128, 3), 256, 0, stream>>>(hB, LD, LD, LD, 0,
          (const int*)nullptr, wtAll + (2 + l) * WTSL, biasAll + (2 + l) * NCP, hA, 1);
      // h = t @ W2[l] + b2[l]  (+relu if l<2)
      gemm_kernel<<<dim3(NN / 128, 3), 256, 0, stream>>>(hA, LD, LD, LD, 0,
          (const int*)nullptr, wtAll + (5 + l) * WTSL, biasAll + (5 + l) * NCP, hB, (l < 2) ? 1 : 0);
      u16* tmp = hA; hA = hB; hB = tmp;
    }
    pool_kernel<<<BB, 320, 0, stream>>>(hA, segs[g], accs[g]);
  }
  combine_kernel<<<4800, 256, 0, stream>>>(out);
}

// Round 6
// 3750.669 us; speedup vs baseline: 1.6520x; 1.0860x over previous
//
#include <hip/hip_runtime.h>

typedef unsigned short u16;
typedef __attribute__((ext_vector_type(8))) short short8;
typedef __attribute__((ext_vector_type(4))) float f32x4;

#define NN 122880   // nodes per graph
#define EE 245760   // edges per graph
#define BB 4096     // reactions
#define HH 300      // hidden
#define LD 320      // padded feature leading dim (mult of 32)
#define NCP 384     // padded out-col count in WT slots
#define WTSL (NCP * LD)   // elements per transposed-weight slot
#define BHSZ (BB * HH)
#define GNB 16      // nodes per gather block
#define GCH 64      // edges per gather LDS pass

__device__ __forceinline__ float b2f(u16 s) {
  union { unsigned int u; float f; } v; v.u = ((unsigned int)s) << 16; return v.f;
}
__device__ __forceinline__ u16 f2b(float f) {
  union { float f; unsigned int u; } v; v.f = f;
  unsigned int r = v.u + 0x7FFFu + ((v.u >> 16) & 1u);
  return (u16)(r >> 16);
}

// ---------------------------------------------------------------------------
// prep: f32 weights -> zero-padded transposed bf16 WT[slot][n(384)][k(320)],
// f32 biases -> padded f32 bias[slot][384]. Slots: 0=Wn 1=We 2..4=W1 5..7=W2
// ---------------------------------------------------------------------------
__global__ __launch_bounds__(256) void prep_kernel(
    const float* __restrict__ Wn, const float* __restrict__ We,
    const float* __restrict__ W1, const float* __restrict__ W2,
    const float* __restrict__ bn, const float* __restrict__ be,
    const float* __restrict__ b1, const float* __restrict__ b2,
    u16* __restrict__ wtAll, float* __restrict__ biasAll)
{
  int idx = blockIdx.x * 256 + threadIdx.x;
  if (idx < 8 * WTSL) {
    int slot = idx / WTSL, rem = idx % WTSL;
    int n = rem / LD, k = rem % LD;
    float v = 0.f;
    if (n < HH) {
      if (slot == 0)      { if (k < 64)  v = Wn[k * HH + n]; }
      else if (slot == 1) { if (k < 16)  v = We[k * HH + n]; }
      else if (slot < 5)  { int l = slot - 2; if (k < HH) v = W1[(l * HH + k) * HH + n]; }
      else                { int l = slot - 5; if (k < HH) v = W2[(l * HH + k) * HH + n]; }
    }
    wtAll[idx] = f2b(v);
  } else {
    int j = idx - 8 * WTSL;
    if (j < 8 * NCP) {
      int slot = j / NCP, n = j % NCP;
      float v = 0.f;
      if (n < HH) {
        const float* bp = (slot == 0) ? bn : (slot == 1) ? be
                         : (slot < 5) ? (b1 + (slot - 2) * HH) : (b2 + (slot - 5) * HH);
        v = bp[n];
      }
      biasAll[j] = v;
    }
  }
}

__global__ __launch_bounds__(256) void zero_kernel(float4* __restrict__ p, int n4) {
  int i = blockIdx.x * 256 + threadIdx.x;
  if (i < n4) p[i] = make_float4(0.f, 0.f, 0.f, 0.f);
}

// ---------------------------------------------------------------------------
// CSR build: cursor doubles as counts; scan converts in place.
// fill writes int2{edge id, src id}, dst-sorted.
// ---------------------------------------------------------------------------
__global__ __launch_bounds__(256) void count_kernel(
    const int* __restrict__ dst, int* __restrict__ cursor)
{
  int e = blockIdx.x * 256 + threadIdx.x;
  if (e < EE) atomicAdd(&cursor[dst[e]], 1);
}

__global__ __launch_bounds__(1024) void scan_kernel(
    int* __restrict__ cursor, int* __restrict__ indptr)
{
  __shared__ int sd[1024];
  const int tid = threadIdx.x;
  const int base = tid * 120;          // 1024 * 120 == NN exactly
  int s = 0;
  for (int i = 0; i < 120; ++i) s += cursor[base + i];
  sd[tid] = s;
  __syncthreads();
  for (int off = 1; off < 1024; off <<= 1) {
    int v = (tid >= off) ? sd[tid - off] : 0;
    __syncthreads();
    sd[tid] += v;
    __syncthreads();
  }
  int run = sd[tid] - s;               // exclusive prefix
  for (int i = 0; i < 120; ++i) {
    int c = cursor[base + i];
    indptr[base + i] = run;
    cursor[base + i] = run;
    run += c;
  }
  if (tid == 1023) indptr[NN] = run;   // == EE
}

__global__ __launch_bounds__(256) void fill_kernel(
    const int* __restrict__ dst, const int* __restrict__ src,
    int* __restrict__ cursor, int2* __restrict__ ess)
{
  int e = blockIdx.x * 256 + threadIdx.x;
  if (e < EE) {
    int pos = atomicAdd(&cursor[dst[e]], 1);
    ess[pos] = make_int2(e, src[e]);
  }
}

// ---------------------------------------------------------------------------
// MFMA GEMM: C[r,c] = op(A[r,:K] @ W[:K,c] + bias[c]), bf16 out.
// A bf16 (a_f32=0) or f32 (a_f32=1, converted in staging). WT: [384][320]
// transposed bf16, zero pads. Block tile 128 rows x 160 cols (grid.y=2 covers
// 320 cols; pads 300..319 store exact 0). 4 waves 2x2, wave = 64x80 = 4x5
// MFMA 16x16x32 tiles.
// ---------------------------------------------------------------------------
__global__ __launch_bounds__(256) void gemm_kernel(
    const void* __restrict__ A, int lda, int K, int a_f32,
    const u16* __restrict__ WT, const float* __restrict__ bias,
    u16* __restrict__ C, int relu)
{
  __shared__ u16 As[128][40];   // +8 pad: rows 80B, 16B-aligned chunks
  __shared__ u16 Bs[160][40];

  const int tid = threadIdx.x;
  const int lane = tid & 63, w = tid >> 6;
  const int wm = (w >> 1) * 64, wn = (w & 1) * 80;
  const int m16 = lane & 15, q = lane >> 4;
  const long r0 = (long)blockIdx.x * 128;
  const int c0 = blockIdx.y * 160;

  f32x4 acc[4][5];
#pragma unroll
  for (int i = 0; i < 4; ++i)
#pragma unroll
    for (int j = 0; j < 5; ++j) acc[i][j] = (f32x4){0.f, 0.f, 0.f, 0.f};

  const int nk = K >> 5;
  for (int kt = 0; kt < nk; ++kt) {
    __syncthreads();
    // A tile: 128 rows x 32 k = 512 8-elem chunks
#pragma unroll
    for (int i = 0; i < 2; ++i) {
      int ci = tid + i * 256;
      int row = ci >> 2, kc = (ci & 3) << 3;
      int kg = (kt << 5) + kc;
      if (a_f32) {
        const float* Af = (const float*)A + (r0 + row) * (long)lda + kg;
        float4 v0 = *(const float4*)Af;
        float4 v1 = *(const float4*)(Af + 4);
        ushort4 p0, p1;
        p0.x = f2b(v0.x); p0.y = f2b(v0.y); p0.z = f2b(v0.z); p0.w = f2b(v0.w);
        p1.x = f2b(v1.x); p1.y = f2b(v1.y); p1.z = f2b(v1.z); p1.w = f2b(v1.w);
        *(ushort4*)&As[row][kc] = p0;
        *(ushort4*)&As[row][kc + 4] = p1;
      } else {
        uint4 av = *(const uint4*)((const u16*)A + (r0 + row) * (long)lda + kg);
        *(uint4*)&As[row][kc] = av;
      }
    }
    // B tile: 160 rows x 32 k = 640 chunks
#pragma unroll
    for (int i = 0; i < 3; ++i) {
      int ci = tid + i * 256;
      if (ci < 640) {
        int row = ci >> 2, kc = (ci & 3) << 3;
        int kg = (kt << 5) + kc;
        uint4 bv = *(const uint4*)(WT + (long)(c0 + row) * LD + kg);
        *(uint4*)&Bs[row][kc] = bv;
      }
    }
    __syncthreads();

    short8 af[4], bf[5];
#pragma unroll
    for (int t = 0; t < 4; ++t) af[t] = *(const short8*)&As[wm + t * 16 + m16][q << 3];
#pragma unroll
    for (int t = 0; t < 5; ++t) bf[t] = *(const short8*)&Bs[wn + t * 16 + m16][q << 3];
#pragma unroll
    for (int tm = 0; tm < 4; ++tm)
#pragma unroll
      for (int tn = 0; tn < 5; ++tn)
        acc[tm][tn] = __builtin_amdgcn_mfma_f32_16x16x32_bf16(af[tm], bf[tn], acc[tm][tn], 0, 0, 0);
  }

  // D row = q*4+i, col = lane&15 (m89/m91-verified C/D layout)
#pragma unroll
  for (int tn = 0; tn < 5; ++tn) {
    int c = c0 + wn + tn * 16 + m16;
    float bv = bias[c];
#pragma unroll
    for (int tm = 0; tm < 4; ++tm) {
      long rbase = r0 + wm + tm * 16 + q * 4;
#pragma unroll
      for (int i = 0; i < 4; ++i) {
        float v = acc[tm][tn][i] + bv;
        if (relu) v = v > 0.f ? v : 0.f;
        C[(rbase + i) * LD + c] = f2b(v);
      }
    }
  }
}

// ---------------------------------------------------------------------------
// gather: z[n] = h[n] + sum_{t: dst-sorted edges of n} relu(h[src]+eraw@We+be)
// Block = GNB consecutive nodes; their edges are contiguous [t0,t1).
// Phase 1: stream <=GCH edges/pass, each thread computes its column of the
// message (We col + bias in registers), store bf16 to LDS — all iterations
// independent. Phase 2: per-node boundary sum from LDS into f32 registers.
// Pad cols (300..319) are exactly 0 everywhere -> no guards needed.
// ---------------------------------------------------------------------------
__global__ __launch_bounds__(320) void gather_kernel(
    const u16* __restrict__ h, const float* __restrict__ eraw,
    const u16* __restrict__ wtE, const float* __restrict__ biasE,
    const int2* __restrict__ ess, const int* __restrict__ indptr,
    u16* __restrict__ z)
{
  __shared__ u16 mS[GCH][320];     // 40 KB
  const int base = blockIdx.x * GNB;
  const int c = threadIdx.x;

  float wreg[16];
  {
    uint4 w0 = *(const uint4*)(wtE + (long)c * LD);
    uint4 w1 = *(const uint4*)(wtE + (long)c * LD + 8);
    const u16* pw0 = (const u16*)&w0;
    const u16* pw1 = (const u16*)&w1;
#pragma unroll
    for (int k = 0; k < 8; ++k) { wreg[k] = b2f(pw0[k]); wreg[8 + k] = b2f(pw1[k]); }
  }
  const float bv = biasE[c];

  int bnd[GNB + 1];                // block-uniform -> SGPRs
#pragma unroll
  for (int i = 0; i <= GNB; ++i) bnd[i] = indptr[base + i];

  float a[GNB];
#pragma unroll
  for (int g = 0; g < GNB; ++g) a[g] = b2f(h[(long)(base + g) * LD + c]);

  const int t0 = bnd[0], t1 = bnd[GNB];
  for (int tc = t0; tc < t1; tc += GCH) {
    const int te = (tc + GCH < t1) ? (tc + GCH) : t1;
    for (int t = tc; t < te; ++t) {
      int2 es = ess[t];
      const float* er = eraw + (long)es.x * 16;
      float4 e0 = *(const float4*)er;
      float4 e1 = *(const float4*)(er + 4);
      float4 e2 = *(const float4*)(er + 8);
      float4 e3 = *(const float4*)(er + 12);
      float m = bv;
      m += e0.x * wreg[0];  m += e0.y * wreg[1];  m += e0.z * wreg[2];  m += e0.w * wreg[3];
      m += e1.x * wreg[4];  m += e1.y * wreg[5];  m += e1.z * wreg[6];  m += e1.w * wreg[7];
      m += e2.x * wreg[8];  m += e2.y * wreg[9];  m += e2.z * wreg[10]; m += e2.w * wreg[11];
      m += e3.x * wreg[12]; m += e3.y * wreg[13]; m += e3.z * wreg[14]; m += e3.w * wreg[15];
      m += b2f(h[(long)es.y * LD + c]);
      mS[t - tc][c] = f2b(m > 0.f ? m : 0.f);
    }
    __syncthreads();
#pragma unroll
    for (int g = 0; g < GNB; ++g) {
      int lo = bnd[g] > tc ? bnd[g] : tc;
      int hi = bnd[g + 1] < te ? bnd[g + 1] : te;
      for (int t = lo; t < hi; ++t) a[g] += b2f(mS[t - tc][c]);
    }
    __syncthreads();
  }
#pragma unroll
  for (int g = 0; g < GNB; ++g)
    z[(long)(base + g) * LD + c] = f2b(a[g]);
}

// ---------------------------------------------------------------------------
// pooling: seg sorted -> block b binary-searches node range, no atomics
// ---------------------------------------------------------------------------
__global__ __launch_bounds__(320) void pool_kernel(
    const u16* __restrict__ h, const int* __restrict__ seg, float* __restrict__ acc)
{
  int b = blockIdx.x;
  int lo, hi;
  { int l = 0, r = NN; while (l < r) { int m = (l + r) >> 1; if (seg[m] < b) l = m + 1; else r = m; } lo = l; }
  { int l = lo, r = NN; while (l < r) { int m = (l + r) >> 1; if (seg[m] < b + 1) l = m + 1; else r = m; } hi = l; }
  int j = threadIdx.x;
  if (j < HH) {
    float s = 0.f;
    for (int n = lo; n < hi; ++n) s += b2f(h[(long)n * LD + j]);
    acc[(long)b * HH + j] += s;
  }
}

// out[0:BHSZ) = r - p, where r lives at out[BHSZ..) and p at out[2*BHSZ..)
__global__ __launch_bounds__(256) void combine_kernel(float* __restrict__ out) {
  int i = blockIdx.x * 256 + threadIdx.x;
  if (i < BHSZ) out[i] = out[BHSZ + i] - out[2 * BHSZ + i];
}

// ---------------------------------------------------------------------------
extern "C" void kernel_launch(void* const* d_in, const int* in_sizes, int n_in,
                              void* d_out, int out_size, void* d_ws, size_t ws_size,
                              hipStream_t stream)
{
  (void)in_sizes; (void)n_in; (void)out_size; (void)ws_size;
  const float* r_x = (const float*)d_in[0];
  const float* r_e = (const float*)d_in[1];
  const float* p_x = (const float*)d_in[2];
  const float* p_e = (const float*)d_in[3];
  const float* Wn  = (const float*)d_in[4];
  const float* bn  = (const float*)d_in[5];
  const float* We  = (const float*)d_in[6];
  const float* be  = (const float*)d_in[7];
  const float* W1  = (const float*)d_in[8];
  const float* b1  = (const float*)d_in[9];
  const float* W2  = (const float*)d_in[10];
  const float* b2  = (const float*)d_in[11];
  const int* r_src = (const int*)d_in[12];
  const int* r_dst = (const int*)d_in[13];
  const int* r_seg = (const int*)d_in[14];
  const int* p_src = (const int*)d_in[15];
  const int* p_dst = (const int*)d_in[16];
  const int* p_seg = (const int*)d_in[17];
  float* out = (float*)d_out;

  // --- workspace layout (~163 MB, proven to fit) ---
  char* ws = (char*)d_ws;
  size_t off = 0;
  auto take = [&](size_t bytes) -> char* {
    char* p = ws + off;
    off = (off + bytes + 255) & ~(size_t)255;
    return p;
  };
  u16*   nb0     = (u16*)  take((size_t)NN * LD * 2);       // h / t ping
  u16*   nb1     = (u16*)  take((size_t)NN * LD * 2);       // z / h pong
  u16*   wtAll   = (u16*)  take((size_t)8 * WTSL * 2);      // transposed weights
  float* biasAll = (float*)take((size_t)8 * NCP * 4);       // padded biases
  int*   indptr  = (int*)  take((size_t)(NN + 1) * 4);
  int*   cursor  = (int*)  take((size_t)NN * 4);
  int2*  ess     = (int2*) take((size_t)EE * 8);            // dst-sorted {eid,src}

  float* r_acc = out + BHSZ;       // pooled reactant sums (f32, output 1)
  float* p_acc = out + 2 * BHSZ;   // pooled product sums  (f32, output 2)

  prep_kernel<<<3852, 256, 0, stream>>>(Wn, We, W1, W2, bn, be, b1, b2, wtAll, biasAll);
  zero_kernel<<<2400, 256, 0, stream>>>((float4*)r_acc, 614400);   // r_acc + p_acc

  const float* xs[3] = { r_x, r_x + (size_t)NN * 64, p_x };
  const float* es[3] = { r_e, r_e + (size_t)EE * 16, p_e };
  const int* srcs[3] = { r_src, r_src + EE, p_src };
  const int* dsts[3] = { r_dst, r_dst + EE, p_dst };
  const int* segs[3] = { r_seg, r_seg + NN, p_seg };
  float*     accs[3] = { r_acc, r_acc, p_acc };

  for (int g = 0; g < 3; ++g) {
    // CSR by dst (reused across the 3 layers of this graph)
    zero_kernel<<<120, 256, 0, stream>>>((float4*)cursor, 30720);
    count_kernel<<<960, 256, 0, stream>>>(dsts[g], cursor);
    scan_kernel<<<1, 1024, 0, stream>>>(cursor, indptr);
    fill_kernel<<<960, 256, 0, stream>>>(dsts[g], srcs[g], cursor, ess);

    // h = relu(x @ Wn + bn)   (f32 A, K=64)
    gemm_kernel<<<dim3(NN / 128, 2), 256, 0, stream>>>(xs[g], 64, 64, 1,
        wtAll, biasAll, nb0, 1);

    u16* hA = nb0; u16* hB = nb1;
    for (int l = 0; l < 3; ++l) {
      gather_kernel<<<NN / GNB, 320, 0, stream>>>(hA, es[g], wtAll + WTSL,
          biasAll + NCP, ess, indptr, hB);
      // t = relu(z @ W1[l] + b1[l])
      gemm_kernel<<<dim3(NN / 128, 2), 256, 0, stream>>>(hB, LD, LD, 0,
          wtAll + (2 + l) * WTSL, biasAll + (2 + l) * NCP, hA, 1);
      // h = t @ W2[l] + b2[l]  (+relu if l<2)
      gemm_kernel<<<dim3(NN / 128, 2), 256, 0, stream>>>(hA, LD, LD, 0,
          wtAll + (5 + l) * WTSL, biasAll + (5 + l) * NCP, hB, (l < 2) ? 1 : 0);
      u16* tmp = hA; hA = hB; hB = tmp;
    }
    pool_kernel<<<BB, 320, 0, stream>>>(hA, segs[g], accs[g]);
  }
  combine_kernel<<<4800, 256, 0, stream>>>(out);
}